// Round 2
// baseline (285.758 us; speedup 1.0000x reference)
//
#include <hip/hip_runtime.h>
#include <cstdint>

#define BB 64
#define PP 8732
#define CC 81
#define PRB 64                         // priors per tile
#define TPB 256                        // threads per block (4 waves)
#define NBX ((PP + PRB - 1) / PRB)     // 137 tiles per batch row
#define BPR 12                         // blocks per batch row (persistent)
#define NBLK (BB * BPR)                // 768 = 3 blocks/CU * 256 CUs
#define NPTAIL (PP - (NBX - 1) * PRB)  // 28

#define GLOBAL_AS __attribute__((address_space(1)))
#define LDS_AS __attribute__((address_space(3)))

// counted vmem wait (T4): keep next tile's DMAs in flight across the barrier
#define WAITV(n) asm volatile("s_waitcnt vmcnt(" #n ")" ::: "memory")
#define CFENCE() asm volatile("" ::: "memory")

// ---------- wave (64-lane) reductions ----------
__device__ __forceinline__ float wsum(float v) {
#pragma unroll
  for (int o = 32; o > 0; o >>= 1) v += __shfl_xor(v, o, 64);
  return v;
}
__device__ __forceinline__ int wsumi(int v) {
#pragma unroll
  for (int o = 32; o > 0; o >>= 1) v += __shfl_xor(v, o, 64);
  return v;
}

// ---------- tile staging: fixed per-wave DMA instruction counts ----------
// Full tile: 64*81 floats = 1296 16B-chunks = 324/wave -> exactly 6 instrs/wave
// (5 full + 1 with lanes 0-3 active). Tail tile (28 priors): 567 chunks,
// 142/wave -> exactly 3 instrs/wave (3rd has >=13 lanes active, exec never 0).
// Uniform per-wave instruction counts make the counted vmcnt sound.
__device__ __forceinline__ void stage_full_t(LDS_AS float* dst,
                                             const GLOBAL_AS float* src,
                                             int wave, int lane) {
  const int start = wave * 324;
#pragma unroll
  for (int t = 0; t < 5; ++t) {
    const int idx = start + t * 64 + lane;
    __builtin_amdgcn_global_load_lds((const GLOBAL_AS void*)(src + 4 * idx),
                                     (LDS_AS void*)(dst + 4 * idx), 16, 0, 0);
  }
  const int idx = start + 320 + lane;
  if (lane < 4)
    __builtin_amdgcn_global_load_lds((const GLOBAL_AS void*)(src + 4 * idx),
                                     (LDS_AS void*)(dst + 4 * idx), 16, 0, 0);
}
__device__ __forceinline__ void stage_tail_t(LDS_AS float* dst,
                                             const GLOBAL_AS float* src,
                                             int wave, int lane) {
  const int start = wave * 142;
  const int end = min(start + 142, 567);
#pragma unroll
  for (int t = 0; t < 2; ++t) {
    const int idx = start + t * 64 + lane;
    __builtin_amdgcn_global_load_lds((const GLOBAL_AS void*)(src + 4 * idx),
                                     (LDS_AS void*)(dst + 4 * idx), 16, 0, 0);
  }
  const int idx = start + 128 + lane;
  if (idx < end)
    __builtin_amdgcn_global_load_lds((const GLOBAL_AS void*)(src + 4 * idx),
                                     (LDS_AS void*)(dst + 4 * idx), 16, 0, 0);
}
__device__ __forceinline__ void stage_tile(float* dstbuf, const float* src0,
                                           bool full, int wave, int lane) {
  LDS_AS float* dst = (LDS_AS float*)dstbuf;
  const GLOBAL_AS float* src = (const GLOBAL_AS float*)src0;
  if (full) stage_full_t(dst, src, wave, lane);
  else      stage_tail_t(dst, src, wave, lane);
}

// ---------- kernel 1: persistent per-row blocks, double-buffered DMA ----------
// 768 blocks = 12 per batch row; block walks tiles bx = r, r+12, ... (11 or 12).
// Per tile: scalars(cur) + stage(next) -> vmcnt(count(next)) -> s_barrier ->
// compute(cur) -> s_barrier. vmcnt never drains to 0 in the main loop, so the
// next tile's 20.7 KB stays in flight under the current tile's compute (T3/T4).
// Counted-wait audit: at WAITV the per-wave outstanding queue is
// [cur 6 (oldest), 3 scalar loads, next 6] = 15; leaving 6 drains cur+scalars.
__global__ __launch_bounds__(TPB) void k_rowstats(
    const float* __restrict__ conf, const float* __restrict__ ploc,
    const int* __restrict__ label, const float* __restrict__ gloc,
    float* __restrict__ negp, int* __restrict__ part_cnt,
    float* __restrict__ part_nll, float* __restrict__ part_loc,
    int* __restrict__ fin_cnt) {
  __shared__ __align__(16) float s_buf[2][PRB * CC];   // 2 x 20736 B
  __shared__ float sh_n[4], sh_l[4];
  __shared__ int sh_c[4];

  const int bid = blockIdx.x;
  const int b = bid / BPR, r = bid - b * BPR;
  const int tid = threadIdx.x, lane = tid & 63, wave = tid >> 6;
  const int p = tid >> 2, q = tid & 3;
  // 137 tiles: chains r<=4 get 12 tiles (137 = 5*12 + 7*11), others 11.
  // Tail tile bx=136 is the LAST tile of chain r=4 only (136 = 4 + 11*12).
  const int ntiles = (r <= 4) ? 12 : 11;

  if (bid == 0 && tid == 0) *fin_cnt = 0;   // stream-ordered ahead of k_topk

  int bx = r;
  stage_tile(s_buf[0], conf + ((size_t)b * PP + (size_t)bx * PRB) * CC,
             bx != NBX - 1, wave, lane);

  float nll_acc = 0.0f, loc_acc = 0.0f;
  int cnt = 0;

  for (int j = 0; j < ntiles; ++j) {
    float* cbuf = s_buf[j & 1];
    const int bxn = bx + BPR;
    const bool hasn = (j + 1 < ntiles);
    const int np = (bx == NBX - 1) ? NPTAIL : PRB;
    const size_t rowbase = (size_t)b * PP + (size_t)bx * PRB;
    const bool act = p < np;

    // scalar loads for the CURRENT tile; drained by the counted wait (or by
    // the compiler's own use-site waitcnt if it reorders them after the stage)
    int lab = 0; float pv = 0.0f, gv = 0.0f;
    if (act) {
      lab = label[rowbase + p];               // 4 lanes same addr -> broadcast
      const size_t i4 = rowbase * 4 + tid;    // coalesced
      pv = ploc[i4]; gv = gloc[i4];
    }

    if (hasn) {
      stage_tile(s_buf[(j + 1) & 1],
                 conf + ((size_t)b * PP + (size_t)bxn * PRB) * CC,
                 bxn != NBX - 1, wave, lane);
      if (bxn != NBX - 1) WAITV(6); else WAITV(3);  // leave next tile in flight
    } else {
      WAITV(0);
    }
    __builtin_amdgcn_sched_barrier(0);
    __builtin_amdgcn_s_barrier();             // all waves' cur-tile DMA landed
    CFENCE();
    __builtin_amdgcn_sched_barrier(0);

    if (act) {
      const float* xr = cbuf + p * CC;
      float s = 0.0f;
      for (int c = q; c < CC; c += 4) s += __expf(xr[c]);
      s += __shfl_xor(s, 1, 64);
      s += __shfl_xor(s, 2, 64);              // all 4 lanes hold full sum
      const float lse = __logf(s);

      const bool pos = lab > 0;
      const float df = pv - gv;
      const float ad = fabsf(df);
      if (pos) loc_acc += (ad < 1.0f) ? 0.5f * df * df : ad - 0.5f;
      if (q == 0) {
        negp[rowbase + p] = pos ? 0.0f : fmaxf(lse - xr[0], 0.0f);
        if (pos) { cnt += 1; nll_acc += lse - xr[lab]; }
      }
    }

    CFENCE();
    __builtin_amdgcn_sched_barrier(0);
    __builtin_amdgcn_s_barrier();             // everyone done reading cbuf
    bx = bxn;
  }

  // ---- one block reduce + one partial store per chain (12 slots/row) ----
  const float na = wsum(nll_acc);
  const float la = wsum(loc_acc);
  const int ca = wsumi(cnt);
  if (lane == 0) { sh_n[wave] = na; sh_l[wave] = la; sh_c[wave] = ca; }
  __syncthreads();
  if (tid == 0) {
    float tn = 0.0f, tl = 0.0f; int tc = 0;
#pragma unroll
    for (int w = 0; w < 4; ++w) { tn += sh_n[w]; tl += sh_l[w]; tc += sh_c[w]; }
    const int slot = b * BPR + r;
    part_cnt[slot] = tc;
    part_nll[slot] = tn;
    part_loc[slot] = tl;
  }
}

// ---------- kernel 2: per-row top-K radix select + fused finalize ----------
#define RREP 16
#define HSTR 257
#define TTK 1024
__global__ __launch_bounds__(TTK) void k_topk(
    const float* __restrict__ negp, const int* __restrict__ part_cnt,
    const float* __restrict__ part_nll, const float* __restrict__ part_loc,
    int* __restrict__ row_npos, float* __restrict__ row_nll,
    float* __restrict__ row_loc, float* __restrict__ row_topk,
    int* __restrict__ fin_cnt, float* __restrict__ out) {
  __shared__ uint32_t s_v[PP];            // 34928 B
  __shared__ int s_hist[RREP * HSTR];     // 16448 B
  __shared__ int s_tot[256];
  __shared__ uint32_t s_pref;
  __shared__ int s_kk;
  __shared__ int s_npos;
  __shared__ int s_last;
  __shared__ float s_redf[TTK / 64];

  const int b = blockIdx.x;
  const int tid = threadIdx.x;
  const int lane = tid & 63, wave = tid >> 6;

  // ---- async DMA stage of the 8732 values (PP = 2183*4, base 16B-aligned)
  {
    const GLOBAL_AS float* g = (const GLOBAL_AS float*)(negp + (size_t)b * PP);
    LDS_AS uint32_t* l = (LDS_AS uint32_t*)s_v;
    for (int i = tid; i < PP / 4; i += TTK)
      __builtin_amdgcn_global_load_lds((const GLOBAL_AS void*)(g + 4 * i),
                                       (LDS_AS void*)(l + 4 * i), 16, 0, 0);
  }

  // ---- overlap: reduce this row's 12 partials + clear pass-0 histogram ----
  if (wave == 0) {
    int c = 0; float n = 0.0f, l = 0.0f;
    if (lane < BPR) {
      const int slot = b * BPR + lane;
      c = part_cnt[slot]; n = part_nll[slot]; l = part_loc[slot];
    }
    const int cc = wsumi(c);
    const float nn = wsum(n);
    const float ll = wsum(l);
    if (lane == 0) { row_npos[b] = cc; row_nll[b] = nn; row_loc[b] = ll; s_npos = cc; }
  }
  for (int i = tid; i < RREP * HSTR; i += TTK) s_hist[i] = 0;
  __syncthreads();                        // drains DMA + publishes s_npos

  const int npos = s_npos;
  int K = 3 * npos;
  const int mx = PP - npos;
  if (K > mx) K = mx;

  if (K > 0) {                            // block-uniform branch
    if (tid == 0) { s_pref = 0u; s_kk = K; }
    __syncthreads();
    const int rep = tid & (RREP - 1);

    for (int pass = 0; pass < 4; ++pass) {
      const int sh = 24 - 8 * pass;
      const uint32_t himask = (pass == 0) ? 0u : (0xFFFFFFFFu << (sh + 8));
      const uint32_t pref = s_pref;
      for (int i = tid; i < PP; i += TTK) {
        const uint32_t u = s_v[i];
        if ((u & himask) == (pref & himask))
          atomicAdd(&s_hist[rep * HSTR + ((u >> sh) & 0xFF)], 1);
      }
      __syncthreads();
      if (tid < 256) {
        int tt = 0;
#pragma unroll
        for (int rr = 0; rr < RREP; ++rr) tt += s_hist[rr * HSTR + tid];
        s_tot[tid] = tt;
      }
      __syncthreads();
      for (int i = tid; i < RREP * HSTR; i += TTK) s_hist[i] = 0;
      // wave-0 parallel suffix-scan: find bin with S(bin) >= kk > S(bin+1)
      if (tid < 64) {
        const int l = tid;
        const int e0 = s_tot[4 * l], e1 = s_tot[4 * l + 1];
        const int e2 = s_tot[4 * l + 2], e3 = s_tot[4 * l + 3];
        const int L = e0 + e1 + e2 + e3;
        int x = L;
#pragma unroll
        for (int o = 1; o < 64; o <<= 1) {
          const int v = __shfl_down(x, o, 64);
          if (l + o < 64) x += v;
        }
        const int T = x - L;
        const int S3 = e3 + T, S2 = e2 + S3, S1 = e1 + S2, S0 = e0 + S1;
        const int kk = s_kk;
        const uint32_t pf = s_pref;
        if (S0 >= kk && S1 < kk) { s_pref = pf | ((uint32_t)(4 * l + 0) << sh); s_kk = kk - S1; }
        if (S1 >= kk && S2 < kk) { s_pref = pf | ((uint32_t)(4 * l + 1) << sh); s_kk = kk - S2; }
        if (S2 >= kk && S3 < kk) { s_pref = pf | ((uint32_t)(4 * l + 2) << sh); s_kk = kk - S3; }
        if (S3 >= kk && T  < kk) { s_pref = pf | ((uint32_t)(4 * l + 3) << sh); s_kk = kk - T; }
      }
      __syncthreads();
    }

    const uint32_t T = s_pref;
    const int kk = s_kk;
    float local = 0.0f;
    for (int i = tid; i < PP; i += TTK) {
      const uint32_t u = s_v[i];
      if (u > T) local += __uint_as_float(u);
    }
    local = wsum(local);
    if (lane == 0) s_redf[wave] = local;
    __syncthreads();
    if (tid == 0) {
      float tot = 0.0f;
#pragma unroll
      for (int w = 0; w < TTK / 64; ++w) tot += s_redf[w];
      row_topk[b] = tot + (float)kk * __uint_as_float(T);
    }
  } else {
    if (tid == 0) row_topk[b] = 0.0f;
  }

  // ---- fused finalize: last block to finish reduces all 64 rows ----
  // Writer: release fence + device-scope atomicAdd. Reader: acquire fence.
  // No co-residency requirement (works regardless of dispatch order).
  if (tid == 0) {
    __threadfence();
    s_last = (atomicAdd(fin_cnt, 1) == BB - 1) ? 1 : 0;
  }
  __syncthreads();
  if (s_last) {
    if (tid < 64) {
      __threadfence();                    // acquire
      const int np_ = row_npos[tid];
      const float nllv = row_nll[tid] + row_topk[tid];
      const float locv = row_loc[tid];
      int Kq = 3 * np_;
      const int mxq = PP - np_;
      if (Kq > mxq) Kq = mxq;
      const float nsel = (float)(np_ + Kq);

      const float tot_nll = wsum(nllv);
      const float tot_loc = wsum(locv);
      const float tot_pos = wsum((float)np_);
      const float tot_sel = wsum(nsel);

      const float ce = tot_nll / fmaxf(tot_sel, 1.0f);
      out[tid] = ce / (float)np_;                            // conf_loss (B,1)
      if (tid == 0) out[BB] = tot_loc / fmaxf(tot_pos, 1.0f); // loc_huber_loss
    }
  }
}

extern "C" void kernel_launch(void* const* d_in, const int* in_sizes, int n_in,
                              void* d_out, int out_size, void* d_ws, size_t ws_size,
                              hipStream_t stream) {
  const float* conf = (const float*)d_in[0];
  const float* ploc = (const float*)d_in[1];
  const int* label = (const int*)d_in[2];
  const float* gloc = (const float*)d_in[3];
  float* out = (float*)d_out;

  float* negp = (float*)d_ws;                          // BB*PP floats
  int* part_cnt = (int*)(negp + (size_t)BB * PP);      // BB*BPR ints
  float* part_nll = (float*)(part_cnt + BB * BPR);     // BB*BPR floats
  float* part_loc = part_nll + BB * BPR;               // BB*BPR floats
  int* row_npos = (int*)(part_loc + BB * BPR);         // BB ints
  float* row_nll = (float*)(row_npos + BB);            // BB floats
  float* row_loc = row_nll + BB;                       // BB floats
  float* row_topk = row_loc + BB;                      // BB floats
  int* fin_cnt = (int*)(row_topk + BB);                // 1 int

  hipLaunchKernelGGL(k_rowstats, dim3(NBLK), dim3(TPB), 0, stream,
                     conf, ploc, label, gloc, negp, part_cnt, part_nll, part_loc,
                     fin_cnt);
  hipLaunchKernelGGL(k_topk, dim3(BB), dim3(TTK), 0, stream,
                     negp, part_cnt, part_nll, part_loc,
                     row_npos, row_nll, row_loc, row_topk, fin_cnt, out);
}